// Round 24
// baseline (128.548 us; speedup 1.0000x reference)
//
#include <hip/hip_runtime.h>
#include <hip/hip_bf16.h>
#include <stdint.h>

typedef __attribute__((ext_vector_type(4)))  float  f32x4;
typedef __attribute__((ext_vector_type(16))) float  f32x16;
typedef __attribute__((ext_vector_type(8)))  __bf16 bf16x8;
typedef __attribute__((ext_vector_type(4)))  float  float4_t;
typedef __attribute__((ext_vector_type(4)))  int    int4_t;

// ---------- helpers ----------

__device__ __forceinline__ short f2bf(float f) {
  uint32_t u = __builtin_bit_cast(uint32_t, f);
  return (short)((u + 0x7FFFu + ((u >> 16) & 1u)) >> 16);
}

__device__ __forceinline__ void gload16(const void* g, void* l) {
  __builtin_amdgcn_global_load_lds(
      (const __attribute__((address_space(1))) void*)g,
      (__attribute__((address_space(3))) void*)l, 16, 0, 0);
}

__device__ __forceinline__ bf16x8 frag_w0(unsigned int w0) {
  union { unsigned int u[4]; bf16x8 v; } t;
  t.u[0] = w0; t.u[1] = 0; t.u[2] = 0; t.u[3] = 0;
  return t.v;
}

// ---------- fused convert + mask scan (unchanged) ----------

__global__ void cvt_scan(const float* __restrict__ x,   short* __restrict__ xo,
                         const float* __restrict__ w1,  short* __restrict__ w1o,
                         const float* __restrict__ w2,  short* __restrict__ w2o,
                         const int* __restrict__ mask, int* __restrict__ invp,
                         int* __restrict__ lens) {
  const int tid = threadIdx.x;
  if (blockIdx.x >= 8448) {
    const int b = blockIdx.x - 8448;
    const int lane = tid & 63, wv = tid >> 6;
    __shared__ int wtot[4];
    const int* mb = mask + (b << 11);
    int4_t a = reinterpret_cast<const int4_t*>(mb)[tid * 2];
    int4_t c = reinterpret_cast<const int4_t*>(mb)[tid * 2 + 1];
    int m[8] = {a[0] ? 1 : 0, a[1] ? 1 : 0, a[2] ? 1 : 0, a[3] ? 1 : 0,
                c[0] ? 1 : 0, c[1] ? 1 : 0, c[2] ? 1 : 0, c[3] ? 1 : 0};
    int tsum = 0;
#pragma unroll
    for (int j = 0; j < 8; ++j) tsum += m[j];
    int inc = tsum;
#pragma unroll
    for (int d = 1; d < 64; d <<= 1) {
      int t = __shfl_up(inc, d);
      if (lane >= d) inc += t;
    }
    if (lane == 63) wtot[wv] = inc;
    __syncthreads();
    int woff = 0;
#pragma unroll
    for (int w = 0; w < 3; ++w) if (w < wv) woff += wtot[w];
    int run = woff + inc - tsum;
#pragma unroll
    for (int j = 0; j < 8; ++j) {
      if (m[j]) { invp[(b << 11) + run] = tid * 8 + j; run += 1; }
    }
    if (tid == 0) lens[b] = wtot[0] + wtot[1] + wtot[2] + wtot[3];
    return;
  }
  int i = blockIdx.x * 256 + tid;
  if (i < 1572864) {
    float4_t v = reinterpret_cast<const float4_t*>(x)[i];
    union { short s[4]; uint64_t u; } o;
    o.s[0] = f2bf(v[0]); o.s[1] = f2bf(v[1]);
    o.s[2] = f2bf(v[2]); o.s[3] = f2bf(v[3]);
    reinterpret_cast<uint64_t*>(xo)[i] = o.u;
  } else if (i < 2015232) {
    i -= 1572864;
    float4_t v = reinterpret_cast<const float4_t*>(w1)[i];
    union { short s[4]; uint64_t u; } o;
    o.s[0] = f2bf(v[0]); o.s[1] = f2bf(v[1]);
    o.s[2] = f2bf(v[2]); o.s[3] = f2bf(v[3]);
    int f = i / 192, k4 = i - f * 192;
    int h = f / 192, c = f - h * 192;
    int dstrow = (c < 64) ? (h * 64 + c) : (768 + h * 128 + (c - 64));
    reinterpret_cast<uint64_t*>(w1o)[dstrow * 192 + k4] = o.u;
  } else if (i < 2162688) {
    i -= 2015232;
    float4_t v = reinterpret_cast<const float4_t*>(w2)[i];
    union { short s[4]; uint64_t u; } o;
    o.s[0] = f2bf(v[0]); o.s[1] = f2bf(v[1]);
    o.s[2] = f2bf(v[2]); o.s[3] = f2bf(v[3]);
    reinterpret_cast<uint64_t*>(w2o)[i] = o.u;
  }
}

// ---------- fused Q + compacted-KV projection, 256x128 tile ----------
// R23 structure; R24 adds PACKED vtb stores: for fixed (mi,ni) the four r
// values land on consecutive sp addresses -> one 8B store instead of four
// 2B scatters (vtb path: 64 -> 16 store instrs/thread).

__global__ __launch_bounds__(256) void gemm_qkv(
    const short* __restrict__ A, const short* __restrict__ Bw,
    short* __restrict__ qb, short* __restrict__ kb, short* __restrict__ vtb,
    const int* __restrict__ invp, const int* __restrict__ lens)
{
  __shared__ __align__(16) short As[3][256 * 32];
  __shared__ __align__(16) short Bs[3][128 * 32];
  const int tid  = threadIdx.x;
  const int lane = tid & 63;
  const int wave = tid >> 6;
  const int wrh  = wave >> 1;
  const int wcq  = wave & 1;
  const int l16  = lane & 15, lhi = lane >> 4;
  const int K = 768;

  const int strow = tid >> 2;
  const int sgx   = ((tid & 3) ^ ((tid >> 3) & 3)) * 8;

  const bool isQ = blockIdx.x < 192;
  int bm, bn, b = 0;
  const short* aSrc[4];
  const short* bG;

  if (isQ) {
    const int nid = ((int)blockIdx.x & 7) * 24 + ((int)blockIdx.x >> 3);
    bm = nid / 6; bn = nid % 6;
#pragma unroll
    for (int i = 0; i < 4; ++i)
      aSrc[i] = A + (int64_t)(bm * 256 + i * 64 + strow) * K + sgx;
    bG = Bw + (int64_t)(bn * 128) * K;
  } else {
    const int id = (int)blockIdx.x - 192;
    bm = id / 48;
    const int rem = id - bm * 48;
    b = rem / 12; bn = rem % 12;
    const int len = lens[b];
    if (bm * 256 >= len) return;
#pragma unroll
    for (int i = 0; i < 4; ++i) {
      int s = invp[(b << 11) + ((bm * 256 + i * 64 + strow) & 2047)] & 2047;
      aSrc[i] = A + (int64_t)((b << 11) + s) * K + sgx;
    }
    bG = Bw + (int64_t)(768 + bn * 128) * K;
  }

  f32x4 acc[8][4] = {};
  const int nt = 24;

  auto STAGE = [&](int buf, int t) {
    const int k0 = t * 32;
#pragma unroll
    for (int i = 0; i < 4; ++i)
      gload16(aSrc[i] + k0, &As[buf][(i * 64 + strow) * 32 + (tid & 3) * 8]);
#pragma unroll
    for (int j = 0; j < 2; ++j)
      gload16(bG + (int64_t)(j * 64 + strow) * K + k0 + sgx,
              &Bs[buf][(j * 64 + strow) * 32 + (tid & 3) * 8]);
  };

  STAGE(0, 0);
  STAGE(1, 1);

  const int rga = (lhi ^ ((l16 >> 1) & 3)) << 3;

  for (int t = 0; t < nt; ++t) {
    if (t < nt - 1) asm volatile("s_waitcnt vmcnt(6)" ::: "memory");
    else            asm volatile("s_waitcnt vmcnt(0)" ::: "memory");
    __builtin_amdgcn_s_barrier();
    if (t + 2 < nt) STAGE((t + 2) % 3, t + 2);

    const short* as_ = As[t % 3];
    const short* bs_ = Bs[t % 3];
    bf16x8 af[8], bfr[4];
#pragma unroll
    for (int mi = 0; mi < 8; ++mi)
      af[mi] = *reinterpret_cast<const bf16x8*>(
          &as_[(wrh * 128 + mi * 16 + l16) * 32 + rga]);
#pragma unroll
    for (int ni = 0; ni < 4; ++ni)
      bfr[ni] = *reinterpret_cast<const bf16x8*>(
          &bs_[(wcq * 64 + ni * 16 + l16) * 32 + rga]);
#pragma unroll
    for (int mi = 0; mi < 8; ++mi)
#pragma unroll
      for (int ni = 0; ni < 4; ++ni)
        acc[mi][ni] = __builtin_amdgcn_mfma_f32_16x16x32_bf16(
            af[mi], bfr[ni], acc[mi][ni], 0, 0, 0);
  }

#pragma unroll
  for (int mi = 0; mi < 8; ++mi)
#pragma unroll
    for (int ni = 0; ni < 4; ++ni) {
      int col = bn * 128 + wcq * 64 + ni * 16 + l16;
      int rbase = wrh * 128 + mi * 16 + lhi * 4;
      if (isQ) {
#pragma unroll
        for (int r = 0; r < 4; ++r) {
          int row = bm * 256 + rbase + r;
          int bq = row >> 11, s = row & 2047;
          int h = col >> 6, d = col & 63;
          qb[(((bq * 12 + h) << 11) + s) * 64 + d] =
              f2bf(acc[mi][ni][r] * 0.18033688f);
        }
      } else {
        int c  = col & 127;
        int bh = b * 12 + bn;
        int sp = bm * 256 + rbase;
        if (c < 64) {
#pragma unroll
          for (int r = 0; r < 4; ++r)
            kb[((bh << 11) + sp + r) * 64 + c] = f2bf(acc[mi][ni][r]);
        } else {
          union { short s[4]; uint64_t u; } o;
          o.s[0] = f2bf(acc[mi][ni][0]); o.s[1] = f2bf(acc[mi][ni][1]);
          o.s[2] = f2bf(acc[mi][ni][2]); o.s[3] = f2bf(acc[mi][ni][3]);
          *reinterpret_cast<uint64_t*>(
              vtb + (((int64_t)bh * 64 + (c - 64)) << 11) + sp) = o.u;
        }
      }
    }
}

// ---------- out-projection GEMM, 256x128 tile (R24) ----------
// Same geometry/pipeline as gemm_qkv's Q path; fp32 epilogue.
// M=8192 -> 32 mtiles x 6 ntiles = 192 blocks (1 round at 2 blocks/CU).

__global__ __launch_bounds__(256) void gemm_out(
    const short* __restrict__ A, const short* __restrict__ Bw,
    float* __restrict__ Cf)
{
  __shared__ __align__(16) short As[3][256 * 32];
  __shared__ __align__(16) short Bs[3][128 * 32];
  const int tid  = threadIdx.x;
  const int lane = tid & 63;
  const int wave = tid >> 6;
  const int wrh  = wave >> 1;
  const int wcq  = wave & 1;
  const int l16  = lane & 15, lhi = lane >> 4;
  const int K = 768, N = 768;

  const int strow = tid >> 2;
  const int sgx   = ((tid & 3) ^ ((tid >> 3) & 3)) * 8;

  const int nid = ((int)blockIdx.x & 7) * 24 + ((int)blockIdx.x >> 3);
  const int bm = nid / 6, bn = nid % 6;

  const short* aSrc[4];
#pragma unroll
  for (int i = 0; i < 4; ++i)
    aSrc[i] = A + (int64_t)(bm * 256 + i * 64 + strow) * K + sgx;
  const short* bG = Bw + (int64_t)(bn * 128) * K;

  f32x4 acc[8][4] = {};
  const int nt = 24;

  auto STAGE = [&](int buf, int t) {
    const int k0 = t * 32;
#pragma unroll
    for (int i = 0; i < 4; ++i)
      gload16(aSrc[i] + k0, &As[buf][(i * 64 + strow) * 32 + (tid & 3) * 8]);
#pragma unroll
    for (int j = 0; j < 2; ++j)
      gload16(bG + (int64_t)(j * 64 + strow) * K + k0 + sgx,
              &Bs[buf][(j * 64 + strow) * 32 + (tid & 3) * 8]);
  };

  STAGE(0, 0);
  STAGE(1, 1);

  const int rga = (lhi ^ ((l16 >> 1) & 3)) << 3;

  for (int t = 0; t < nt; ++t) {
    if (t < nt - 1) asm volatile("s_waitcnt vmcnt(6)" ::: "memory");
    else            asm volatile("s_waitcnt vmcnt(0)" ::: "memory");
    __builtin_amdgcn_s_barrier();
    if (t + 2 < nt) STAGE((t + 2) % 3, t + 2);

    const short* as_ = As[t % 3];
    const short* bs_ = Bs[t % 3];
    bf16x8 af[8], bfr[4];
#pragma unroll
    for (int mi = 0; mi < 8; ++mi)
      af[mi] = *reinterpret_cast<const bf16x8*>(
          &as_[(wrh * 128 + mi * 16 + l16) * 32 + rga]);
#pragma unroll
    for (int ni = 0; ni < 4; ++ni)
      bfr[ni] = *reinterpret_cast<const bf16x8*>(
          &bs_[(wcq * 64 + ni * 16 + l16) * 32 + rga]);
#pragma unroll
    for (int mi = 0; mi < 8; ++mi)
#pragma unroll
      for (int ni = 0; ni < 4; ++ni)
        acc[mi][ni] = __builtin_amdgcn_mfma_f32_16x16x32_bf16(
            af[mi], bfr[ni], acc[mi][ni], 0, 0, 0);
  }

#pragma unroll
  for (int mi = 0; mi < 8; ++mi)
#pragma unroll
    for (int ni = 0; ni < 4; ++ni) {
      int col = bn * 128 + wcq * 64 + ni * 16 + l16;
#pragma unroll
      for (int r = 0; r < 4; ++r) {
        int row = bm * 256 + wrh * 128 + mi * 16 + lhi * 4 + r;
        Cf[(int64_t)row * N + col] = acc[mi][ni][r];
      }
    }
}

// ---------- flash attention over COMPACTED K/V (unchanged) ----------

__global__ __launch_bounds__(256, 2) void attn_kernel(
    const short* __restrict__ Qb, const short* __restrict__ Kb,
    const short* __restrict__ VTb, const int* __restrict__ lens,
    short* __restrict__ AO)
{
  __shared__ __align__(16) char Ks[3][8192];
  __shared__ __align__(16) char Vs[3][8192];

  const int tid  = threadIdx.x;
  const int lane = tid & 63;
  const int wave = tid >> 6;
  const int l32  = lane & 31;
  const int hi   = lane >> 5;

  const int blk  = blockIdx.x;
  const int xcd  = blk & 7;
  const int slot = blk >> 3;
  const int bh   = xcd * 6 + (slot % 6);
  const int qt   = slot / 6;
  const int b    = bh / 12, h = bh - b * 12;
  const int qrow = qt * 128 + wave * 32 + l32;

  const short* Qp  = Qb + ((int64_t)bh * 2048 + qrow) * 64;
  const char*  KpB = (const char*)(Kb + (int64_t)bh * 2048 * 64);
  const char*  VpB = (const char*)(VTb + (int64_t)bh * 64 * 2048);

  const int len = lens[b];
  const int nt  = (len + 63) >> 6;

  bf16x8 qf[4];
#pragma unroll
  for (int ks = 0; ks < 4; ++ks)
    qf[ks] = *reinterpret_cast<const bf16x8*>(Qp + ks * 16 + hi * 8);

  const int str = tid >> 3;
  const int stc = tid & 7;
  const char* kSrc[2]; const char* vSrc[2]; int ldst[2];
#pragma unroll
  for (int s = 0; s < 2; ++s) {
    int r  = s * 32 + str;
    int cx = (stc ^ (r & 7)) << 4;
    kSrc[s] = KpB + (int64_t)r * 128 + cx;
    vSrc[s] = VpB + (int64_t)r * 4096 + cx;
    ldst[s] = s * 4096 + tid * 16;
  }

  auto STAGE = [&](int buf, int k0) {
#pragma unroll
    for (int s = 0; s < 2; ++s) {
      gload16(kSrc[s] + (int64_t)k0 * 128, &Ks[buf][ldst[s]]);
      gload16(vSrc[s] + (int64_t)k0 * 2,   &Vs[buf][ldst[s]]);
    }
  };

  const bf16x8 qb5 = frag_w0(hi == 0 ? 0x3f80u : 0u);

  f32x16 o0 = {}, o1 = {};
  float lsum = 0.f;

  STAGE(0, 0);
  if (nt > 1) STAGE(1, 64);

  for (int kt = 0; kt < nt; ++kt) {
    const int cur = kt % 3;
    const int k0  = kt * 64;
    if (kt < nt - 1) asm volatile("s_waitcnt vmcnt(4)" ::: "memory");
    else             asm volatile("s_waitcnt vmcnt(0)" ::: "memory");
    __builtin_amdgcn_s_barrier();

    if (kt + 2 < nt) STAGE((kt + 2) % 3, (kt + 2) * 64);

    const char* kb_ = Ks[cur];
    const char* vb_ = Vs[cur];

    f32x16 st[2];
    __builtin_amdgcn_s_setprio(1);
#pragma unroll
    for (int kt2 = 0; kt2 < 2; ++kt2) {
      const int key = k0 + kt2 * 32 + l32;
      unsigned int bw = (key < len) ? 0xC140u : 0xC661u;
      f32x16 z = {};
      z = __builtin_amdgcn_mfma_f32_32x32x16_bf16(
              frag_w0(hi == 0 ? bw : 0u), qb5, z, 0, 0, 0);
      const int r = kt2 * 32 + l32;
#pragma unroll
      for (int ks = 0; ks < 4; ++ks) {
        bf16x8 kf = *reinterpret_cast<const bf16x8*>(
            &kb_[r * 128 + (((ks * 2 + hi) ^ (r & 7)) << 4)]);
        z = __builtin_amdgcn_mfma_f32_32x32x16_bf16(kf, qf[ks], z, 0, 0, 0);
      }
      st[kt2] = z;
    }
    __builtin_amdgcn_s_setprio(0);

    float psum = 0.f;
#pragma unroll
    for (int i = 0; i < 16; ++i) {
      float p = __builtin_amdgcn_exp2f(st[0][i]); st[0][i] = p; psum += p;
    }
#pragma unroll
    for (int i = 0; i < 16; ++i) {
      float p = __builtin_amdgcn_exp2f(st[1][i]); st[1][i] = p; psum += p;
    }
    lsum += psum;

    bf16x8 pb[4];
#pragma unroll
    for (int w = 0; w < 4; ++w) {
      const f32x16& S = st[w >> 1];
      const int rb = (w & 1) * 8;
      unsigned int d01, d23, d45, d67;
      asm("v_cvt_pk_bf16_f32 %0, %1, %2" : "=v"(d01) : "v"(S[rb + 0]), "v"(S[rb + 1]));
      asm("v_cvt_pk_bf16_f32 %0, %1, %2" : "=v"(d23) : "v"(S[rb + 2]), "v"(S[rb + 3]));
      asm("v_cvt_pk_bf16_f32 %0, %1, %2" : "=v"(d45) : "v"(S[rb + 4]), "v"(S[rb + 5]));
      asm("v_cvt_pk_bf16_f32 %0, %1, %2" : "=v"(d67) : "v"(S[rb + 6]), "v"(S[rb + 7]));
      asm("v_permlane32_swap_b32 %0, %1" : "+v"(d01), "+v"(d45));
      asm("v_permlane32_swap_b32 %0, %1" : "+v"(d23), "+v"(d67));
      union { unsigned int u[4]; bf16x8 v; } t;
      t.u[0] = d01; t.u[1] = d23; t.u[2] = d45; t.u[3] = d67;
      pb[w] = t.v;
    }

    __builtin_amdgcn_s_setprio(1);
#pragma unroll
    for (int ks = 0; ks < 4; ++ks) {
      const int r0 = l32, r1 = 32 + l32;
      bf16x8 va0 = *reinterpret_cast<const bf16x8*>(
          &vb_[r0 * 128 + (((ks * 2 + hi) ^ (r0 & 7)) << 4)]);
      o0 = __builtin_amdgcn_mfma_f32_32x32x16_bf16(va0, pb[ks], o0, 0, 0, 0);
      bf16x8 va1 = *reinterpret_cast<const bf16x8*>(
          &vb_[r1 * 128 + (((ks * 2 + hi) ^ (r1 & 7)) << 4)]);
      o1 = __builtin_amdgcn_mfma_f32_32x32x16_bf16(va1, pb[ks], o1, 0, 0, 0);
    }
    __builtin_amdgcn_s_setprio(0);
  }

  float lrun = lsum + __shfl_xor(lsum, 32);
  float inv  = 1.0f / lrun;
  short* Orow = AO + ((int64_t)(b * 2048) + qrow) * 768 + h * 64;
#pragma unroll
  for (int dt = 0; dt < 2; ++dt) {
    const f32x16& O = dt ? o1 : o0;
#pragma unroll
    for (int rp = 0; rp < 8; ++rp) {
      int dbase = dt * 32 + (rp & 1) * 2 + (rp >> 1) * 8 + hi * 4;
      float a = O[2 * rp] * inv, bvl = O[2 * rp + 1] * inv;
      unsigned int wpk;
      asm("v_cvt_pk_bf16_f32 %0, %1, %2" : "=v"(wpk) : "v"(a), "v"(bvl));
      *reinterpret_cast<unsigned int*>(Orow + dbase) = wpk;
    }
  }
}

// ---------- launch ----------

extern "C" void kernel_launch(void* const* d_in, const int* in_sizes, int n_in,
                              void* d_out, int out_size, void* d_ws, size_t ws_size,
                              hipStream_t stream) {
  const float* x    = (const float*)d_in[0];
  const float* wqkv = (const float*)d_in[1];
  const float* wout = (const float*)d_in[2];
  const int*   mask = (const int*)d_in[3];
  float* out = (float*)d_out;

  char* ws = (char*)d_ws;
  short* Qb  = (short*)(ws + 0);          // 12.58 MB
  short* Kb  = (short*)(ws + 12582912);   // compacted keys
  short* VT  = (short*)(ws + 25165824);   // [bh][d][s'] compacted
  short* Xbf = (short*)(ws + 37748736);   // x bf16; reused as attn-out bf16
  short* Wq  = (short*)(ws + 50331648);   // permuted: [Q 768 | KV 1536] rows
  short* Wo  = (short*)(ws + 53870592);
  int*   Invp = (int*)(ws + 55050240);    // 4*2048 ints
  int*   Lens = (int*)(ws + 55083008);    // 4 ints

  cvt_scan<<<8452, 256, 0, stream>>>(x, Xbf, wqkv, Wq, wout, Wo,
                                     mask, Invp, Lens);

  gemm_qkv<<<576, 256, 0, stream>>>(Xbf, Wq, Qb, Kb, VT, Invp, Lens);

  attn_kernel<<<48 * 16, 256, 0, stream>>>(Qb, Kb, VT, Lens, Xbf);

  gemm_out<<<192, 256, 0, stream>>>(Xbf, Wo, out);
}

// Round 25
// 114.910 us; speedup vs baseline: 1.1187x; 1.1187x over previous
//
#include <hip/hip_runtime.h>
#include <hip/hip_bf16.h>
#include <stdint.h>

typedef __attribute__((ext_vector_type(4)))  float  f32x4;
typedef __attribute__((ext_vector_type(16))) float  f32x16;
typedef __attribute__((ext_vector_type(8)))  __bf16 bf16x8;
typedef __attribute__((ext_vector_type(4)))  float  float4_t;
typedef __attribute__((ext_vector_type(4)))  int    int4_t;

// ---------- helpers ----------

__device__ __forceinline__ short f2bf(float f) {
  uint32_t u = __builtin_bit_cast(uint32_t, f);
  return (short)((u + 0x7FFFu + ((u >> 16) & 1u)) >> 16);
}

__device__ __forceinline__ void gload16(const void* g, void* l) {
  __builtin_amdgcn_global_load_lds(
      (const __attribute__((address_space(1))) void*)g,
      (__attribute__((address_space(3))) void*)l, 16, 0, 0);
}

__device__ __forceinline__ bf16x8 frag_w0(unsigned int w0) {
  union { unsigned int u[4]; bf16x8 v; } t;
  t.u[0] = w0; t.u[1] = 0; t.u[2] = 0; t.u[3] = 0;
  return t.v;
}

// ---------- fused convert + mask scan (unchanged) ----------

__global__ void cvt_scan(const float* __restrict__ x,   short* __restrict__ xo,
                         const float* __restrict__ w1,  short* __restrict__ w1o,
                         const float* __restrict__ w2,  short* __restrict__ w2o,
                         const int* __restrict__ mask, int* __restrict__ invp,
                         int* __restrict__ lens) {
  const int tid = threadIdx.x;
  if (blockIdx.x >= 8448) {
    const int b = blockIdx.x - 8448;
    const int lane = tid & 63, wv = tid >> 6;
    __shared__ int wtot[4];
    const int* mb = mask + (b << 11);
    int4_t a = reinterpret_cast<const int4_t*>(mb)[tid * 2];
    int4_t c = reinterpret_cast<const int4_t*>(mb)[tid * 2 + 1];
    int m[8] = {a[0] ? 1 : 0, a[1] ? 1 : 0, a[2] ? 1 : 0, a[3] ? 1 : 0,
                c[0] ? 1 : 0, c[1] ? 1 : 0, c[2] ? 1 : 0, c[3] ? 1 : 0};
    int tsum = 0;
#pragma unroll
    for (int j = 0; j < 8; ++j) tsum += m[j];
    int inc = tsum;
#pragma unroll
    for (int d = 1; d < 64; d <<= 1) {
      int t = __shfl_up(inc, d);
      if (lane >= d) inc += t;
    }
    if (lane == 63) wtot[wv] = inc;
    __syncthreads();
    int woff = 0;
#pragma unroll
    for (int w = 0; w < 3; ++w) if (w < wv) woff += wtot[w];
    int run = woff + inc - tsum;
#pragma unroll
    for (int j = 0; j < 8; ++j) {
      if (m[j]) { invp[(b << 11) + run] = tid * 8 + j; run += 1; }
    }
    if (tid == 0) lens[b] = wtot[0] + wtot[1] + wtot[2] + wtot[3];
    return;
  }
  int i = blockIdx.x * 256 + tid;
  if (i < 1572864) {
    float4_t v = reinterpret_cast<const float4_t*>(x)[i];
    union { short s[4]; uint64_t u; } o;
    o.s[0] = f2bf(v[0]); o.s[1] = f2bf(v[1]);
    o.s[2] = f2bf(v[2]); o.s[3] = f2bf(v[3]);
    reinterpret_cast<uint64_t*>(xo)[i] = o.u;
  } else if (i < 2015232) {
    i -= 1572864;
    float4_t v = reinterpret_cast<const float4_t*>(w1)[i];
    union { short s[4]; uint64_t u; } o;
    o.s[0] = f2bf(v[0]); o.s[1] = f2bf(v[1]);
    o.s[2] = f2bf(v[2]); o.s[3] = f2bf(v[3]);
    int f = i / 192, k4 = i - f * 192;
    int h = f / 192, c = f - h * 192;
    int dstrow = (c < 64) ? (h * 64 + c) : (768 + h * 128 + (c - 64));
    reinterpret_cast<uint64_t*>(w1o)[dstrow * 192 + k4] = o.u;
  } else if (i < 2162688) {
    i -= 2015232;
    float4_t v = reinterpret_cast<const float4_t*>(w2)[i];
    union { short s[4]; uint64_t u; } o;
    o.s[0] = f2bf(v[0]); o.s[1] = f2bf(v[1]);
    o.s[2] = f2bf(v[2]); o.s[3] = f2bf(v[3]);
    reinterpret_cast<uint64_t*>(w2o)[i] = o.u;
  }
}

// ---------- fused Q + compacted-KV projection, 256x128 tile (R24, kept) ----------
// Packed vtb stores: four r values -> one 8B store.

__global__ __launch_bounds__(256) void gemm_qkv(
    const short* __restrict__ A, const short* __restrict__ Bw,
    short* __restrict__ qb, short* __restrict__ kb, short* __restrict__ vtb,
    const int* __restrict__ invp, const int* __restrict__ lens)
{
  __shared__ __align__(16) short As[3][256 * 32];
  __shared__ __align__(16) short Bs[3][128 * 32];
  const int tid  = threadIdx.x;
  const int lane = tid & 63;
  const int wave = tid >> 6;
  const int wrh  = wave >> 1;
  const int wcq  = wave & 1;
  const int l16  = lane & 15, lhi = lane >> 4;
  const int K = 768;

  const int strow = tid >> 2;
  const int sgx   = ((tid & 3) ^ ((tid >> 3) & 3)) * 8;

  const bool isQ = blockIdx.x < 192;
  int bm, bn, b = 0;
  const short* aSrc[4];
  const short* bG;

  if (isQ) {
    const int nid = ((int)blockIdx.x & 7) * 24 + ((int)blockIdx.x >> 3);
    bm = nid / 6; bn = nid % 6;
#pragma unroll
    for (int i = 0; i < 4; ++i)
      aSrc[i] = A + (int64_t)(bm * 256 + i * 64 + strow) * K + sgx;
    bG = Bw + (int64_t)(bn * 128) * K;
  } else {
    const int id = (int)blockIdx.x - 192;
    bm = id / 48;
    const int rem = id - bm * 48;
    b = rem / 12; bn = rem % 12;
    const int len = lens[b];
    if (bm * 256 >= len) return;
#pragma unroll
    for (int i = 0; i < 4; ++i) {
      int s = invp[(b << 11) + ((bm * 256 + i * 64 + strow) & 2047)] & 2047;
      aSrc[i] = A + (int64_t)((b << 11) + s) * K + sgx;
    }
    bG = Bw + (int64_t)(768 + bn * 128) * K;
  }

  f32x4 acc[8][4] = {};
  const int nt = 24;

  auto STAGE = [&](int buf, int t) {
    const int k0 = t * 32;
#pragma unroll
    for (int i = 0; i < 4; ++i)
      gload16(aSrc[i] + k0, &As[buf][(i * 64 + strow) * 32 + (tid & 3) * 8]);
#pragma unroll
    for (int j = 0; j < 2; ++j)
      gload16(bG + (int64_t)(j * 64 + strow) * K + k0 + sgx,
              &Bs[buf][(j * 64 + strow) * 32 + (tid & 3) * 8]);
  };

  STAGE(0, 0);
  STAGE(1, 1);

  const int rga = (lhi ^ ((l16 >> 1) & 3)) << 3;

  for (int t = 0; t < nt; ++t) {
    if (t < nt - 1) asm volatile("s_waitcnt vmcnt(6)" ::: "memory");
    else            asm volatile("s_waitcnt vmcnt(0)" ::: "memory");
    __builtin_amdgcn_s_barrier();
    if (t + 2 < nt) STAGE((t + 2) % 3, t + 2);

    const short* as_ = As[t % 3];
    const short* bs_ = Bs[t % 3];
    bf16x8 af[8], bfr[4];
#pragma unroll
    for (int mi = 0; mi < 8; ++mi)
      af[mi] = *reinterpret_cast<const bf16x8*>(
          &as_[(wrh * 128 + mi * 16 + l16) * 32 + rga]);
#pragma unroll
    for (int ni = 0; ni < 4; ++ni)
      bfr[ni] = *reinterpret_cast<const bf16x8*>(
          &bs_[(wcq * 64 + ni * 16 + l16) * 32 + rga]);
#pragma unroll
    for (int mi = 0; mi < 8; ++mi)
#pragma unroll
      for (int ni = 0; ni < 4; ++ni)
        acc[mi][ni] = __builtin_amdgcn_mfma_f32_16x16x32_bf16(
            af[mi], bfr[ni], acc[mi][ni], 0, 0, 0);
  }

#pragma unroll
  for (int mi = 0; mi < 8; ++mi)
#pragma unroll
    for (int ni = 0; ni < 4; ++ni) {
      int col = bn * 128 + wcq * 64 + ni * 16 + l16;
      int rbase = wrh * 128 + mi * 16 + lhi * 4;
      if (isQ) {
#pragma unroll
        for (int r = 0; r < 4; ++r) {
          int row = bm * 256 + rbase + r;
          int bq = row >> 11, s = row & 2047;
          int h = col >> 6, d = col & 63;
          qb[(((bq * 12 + h) << 11) + s) * 64 + d] =
              f2bf(acc[mi][ni][r] * 0.18033688f);
        }
      } else {
        int c  = col & 127;
        int bh = b * 12 + bn;
        int sp = bm * 256 + rbase;
        if (c < 64) {
#pragma unroll
          for (int r = 0; r < 4; ++r)
            kb[((bh << 11) + sp + r) * 64 + c] = f2bf(acc[mi][ni][r]);
        } else {
          union { short s[4]; uint64_t u; } o;
          o.s[0] = f2bf(acc[mi][ni][0]); o.s[1] = f2bf(acc[mi][ni][1]);
          o.s[2] = f2bf(acc[mi][ni][2]); o.s[3] = f2bf(acc[mi][ni][3]);
          *reinterpret_cast<uint64_t*>(
              vtb + (((int64_t)bh * 64 + (c - 64)) << 11) + sp) = o.u;
        }
      }
    }
}

// ---------- out-projection GEMM: R20 128^2 restored (R24's 256-tile left
// 64 CUs idle + 1 wave/SIMD -> regressed; 384 blocks @ 3/CU is the proven
// config, ~17 us) ----------

__global__ __launch_bounds__(256) void gemm_out(
    const short* __restrict__ A, const short* __restrict__ Bw,
    float* __restrict__ Cf, int M, int N, int K)
{
  __shared__ __align__(16) short As[3][128 * 32];
  __shared__ __align__(16) short Bs[3][128 * 32];
  const int tid  = threadIdx.x;
  const int lane = tid & 63;
  const int wave = tid >> 6;
  const int ntn  = N >> 7;
  const int cpx  = gridDim.x >> 3;
  const int nid  = (blockIdx.x & 7) * cpx + (blockIdx.x >> 3);
  const int bm   = nid / ntn;
  const int bn   = nid % ntn;
  const int wr   = wave >> 1, wc = wave & 1;
  const int l16  = lane & 15, lhi = lane >> 4;

  f32x4 acc[4][4] = {};

  const int srow = lane >> 2;
  const int sg   = lane & 3;
  const int sgx  = (sg ^ ((srow >> 1) & 3)) * 8;
  const short* aG = A  + (int64_t)(bm * 128) * K;
  const short* bG = Bw + (int64_t)(bn * 128) * K;
  const int nt = K >> 5;

  auto STAGE = [&](int buf, int t) {
    const int k0 = t * 32;
#pragma unroll
    for (int i = 0; i < 2; ++i) {
      int rr = wave * 32 + i * 16 + srow;
      gload16(aG + (int64_t)rr * K + k0 + sgx,
              &As[buf][(wave * 32 + i * 16) * 32 + lane * 8]);
      gload16(bG + (int64_t)rr * K + k0 + sgx,
              &Bs[buf][(wave * 32 + i * 16) * 32 + lane * 8]);
    }
  };

  STAGE(0, 0);
  STAGE(1, 1);

  const int rga = (lhi ^ ((l16 >> 1) & 3)) << 3;

  for (int t = 0; t < nt; ++t) {
    if (t < nt - 1) asm volatile("s_waitcnt vmcnt(4)" ::: "memory");
    else            asm volatile("s_waitcnt vmcnt(0)" ::: "memory");
    __builtin_amdgcn_s_barrier();
    if (t + 2 < nt) STAGE((t + 2) % 3, t + 2);

    const short* as_ = As[t % 3];
    const short* bs_ = Bs[t % 3];
    bf16x8 af[4], bfr[4];
#pragma unroll
    for (int mi = 0; mi < 4; ++mi)
      af[mi] = *reinterpret_cast<const bf16x8*>(
          &as_[(wr * 64 + mi * 16 + l16) * 32 + rga]);
#pragma unroll
    for (int ni = 0; ni < 4; ++ni)
      bfr[ni] = *reinterpret_cast<const bf16x8*>(
          &bs_[(wc * 64 + ni * 16 + l16) * 32 + rga]);
#pragma unroll
    for (int mi = 0; mi < 4; ++mi)
#pragma unroll
      for (int ni = 0; ni < 4; ++ni)
        acc[mi][ni] = __builtin_amdgcn_mfma_f32_16x16x32_bf16(
            af[mi], bfr[ni], acc[mi][ni], 0, 0, 0);
  }

#pragma unroll
  for (int mi = 0; mi < 4; ++mi)
#pragma unroll
    for (int ni = 0; ni < 4; ++ni) {
      int col = bn * 128 + wc * 64 + ni * 16 + l16;
#pragma unroll
      for (int r = 0; r < 4; ++r) {
        int row = bm * 128 + wr * 64 + mi * 16 + lhi * 4 + r;
        Cf[(int64_t)row * N + col] = acc[mi][ni][r];
      }
    }
}

// ---------- flash attention over COMPACTED K/V (unchanged) ----------

__global__ __launch_bounds__(256, 2) void attn_kernel(
    const short* __restrict__ Qb, const short* __restrict__ Kb,
    const short* __restrict__ VTb, const int* __restrict__ lens,
    short* __restrict__ AO)
{
  __shared__ __align__(16) char Ks[3][8192];
  __shared__ __align__(16) char Vs[3][8192];

  const int tid  = threadIdx.x;
  const int lane = tid & 63;
  const int wave = tid >> 6;
  const int l32  = lane & 31;
  const int hi   = lane >> 5;

  const int blk  = blockIdx.x;
  const int xcd  = blk & 7;
  const int slot = blk >> 3;
  const int bh   = xcd * 6 + (slot % 6);
  const int qt   = slot / 6;
  const int b    = bh / 12, h = bh - b * 12;
  const int qrow = qt * 128 + wave * 32 + l32;

  const short* Qp  = Qb + ((int64_t)bh * 2048 + qrow) * 64;
  const char*  KpB = (const char*)(Kb + (int64_t)bh * 2048 * 64);
  const char*  VpB = (const char*)(VTb + (int64_t)bh * 64 * 2048);

  const int len = lens[b];
  const int nt  = (len + 63) >> 6;

  bf16x8 qf[4];
#pragma unroll
  for (int ks = 0; ks < 4; ++ks)
    qf[ks] = *reinterpret_cast<const bf16x8*>(Qp + ks * 16 + hi * 8);

  const int str = tid >> 3;
  const int stc = tid & 7;
  const char* kSrc[2]; const char* vSrc[2]; int ldst[2];
#pragma unroll
  for (int s = 0; s < 2; ++s) {
    int r  = s * 32 + str;
    int cx = (stc ^ (r & 7)) << 4;
    kSrc[s] = KpB + (int64_t)r * 128 + cx;
    vSrc[s] = VpB + (int64_t)r * 4096 + cx;
    ldst[s] = s * 4096 + tid * 16;
  }

  auto STAGE = [&](int buf, int k0) {
#pragma unroll
    for (int s = 0; s < 2; ++s) {
      gload16(kSrc[s] + (int64_t)k0 * 128, &Ks[buf][ldst[s]]);
      gload16(vSrc[s] + (int64_t)k0 * 2,   &Vs[buf][ldst[s]]);
    }
  };

  const bf16x8 qb5 = frag_w0(hi == 0 ? 0x3f80u : 0u);

  f32x16 o0 = {}, o1 = {};
  float lsum = 0.f;

  STAGE(0, 0);
  if (nt > 1) STAGE(1, 64);

  for (int kt = 0; kt < nt; ++kt) {
    const int cur = kt % 3;
    const int k0  = kt * 64;
    if (kt < nt - 1) asm volatile("s_waitcnt vmcnt(4)" ::: "memory");
    else             asm volatile("s_waitcnt vmcnt(0)" ::: "memory");
    __builtin_amdgcn_s_barrier();

    if (kt + 2 < nt) STAGE((kt + 2) % 3, (kt + 2) * 64);

    const char* kb_ = Ks[cur];
    const char* vb_ = Vs[cur];

    f32x16 st[2];
    __builtin_amdgcn_s_setprio(1);
#pragma unroll
    for (int kt2 = 0; kt2 < 2; ++kt2) {
      const int key = k0 + kt2 * 32 + l32;
      unsigned int bw = (key < len) ? 0xC140u : 0xC661u;
      f32x16 z = {};
      z = __builtin_amdgcn_mfma_f32_32x32x16_bf16(
              frag_w0(hi == 0 ? bw : 0u), qb5, z, 0, 0, 0);
      const int r = kt2 * 32 + l32;
#pragma unroll
      for (int ks = 0; ks < 4; ++ks) {
        bf16x8 kf = *reinterpret_cast<const bf16x8*>(
            &kb_[r * 128 + (((ks * 2 + hi) ^ (r & 7)) << 4)]);
        z = __builtin_amdgcn_mfma_f32_32x32x16_bf16(kf, qf[ks], z, 0, 0, 0);
      }
      st[kt2] = z;
    }
    __builtin_amdgcn_s_setprio(0);

    float psum = 0.f;
#pragma unroll
    for (int i = 0; i < 16; ++i) {
      float p = __builtin_amdgcn_exp2f(st[0][i]); st[0][i] = p; psum += p;
    }
#pragma unroll
    for (int i = 0; i < 16; ++i) {
      float p = __builtin_amdgcn_exp2f(st[1][i]); st[1][i] = p; psum += p;
    }
    lsum += psum;

    bf16x8 pb[4];
#pragma unroll
    for (int w = 0; w < 4; ++w) {
      const f32x16& S = st[w >> 1];
      const int rb = (w & 1) * 8;
      unsigned int d01, d23, d45, d67;
      asm("v_cvt_pk_bf16_f32 %0, %1, %2" : "=v"(d01) : "v"(S[rb + 0]), "v"(S[rb + 1]));
      asm("v_cvt_pk_bf16_f32 %0, %1, %2" : "=v"(d23) : "v"(S[rb + 2]), "v"(S[rb + 3]));
      asm("v_cvt_pk_bf16_f32 %0, %1, %2" : "=v"(d45) : "v"(S[rb + 4]), "v"(S[rb + 5]));
      asm("v_cvt_pk_bf16_f32 %0, %1, %2" : "=v"(d67) : "v"(S[rb + 6]), "v"(S[rb + 7]));
      asm("v_permlane32_swap_b32 %0, %1" : "+v"(d01), "+v"(d45));
      asm("v_permlane32_swap_b32 %0, %1" : "+v"(d23), "+v"(d67));
      union { unsigned int u[4]; bf16x8 v; } t;
      t.u[0] = d01; t.u[1] = d23; t.u[2] = d45; t.u[3] = d67;
      pb[w] = t.v;
    }

    __builtin_amdgcn_s_setprio(1);
#pragma unroll
    for (int ks = 0; ks < 4; ++ks) {
      const int r0 = l32, r1 = 32 + l32;
      bf16x8 va0 = *reinterpret_cast<const bf16x8*>(
          &vb_[r0 * 128 + (((ks * 2 + hi) ^ (r0 & 7)) << 4)]);
      o0 = __builtin_amdgcn_mfma_f32_32x32x16_bf16(va0, pb[ks], o0, 0, 0, 0);
      bf16x8 va1 = *reinterpret_cast<const bf16x8*>(
          &vb_[r1 * 128 + (((ks * 2 + hi) ^ (r1 & 7)) << 4)]);
      o1 = __builtin_amdgcn_mfma_f32_32x32x16_bf16(va1, pb[ks], o1, 0, 0, 0);
    }
    __builtin_amdgcn_s_setprio(0);
  }

  float lrun = lsum + __shfl_xor(lsum, 32);
  float inv  = 1.0f / lrun;
  short* Orow = AO + ((int64_t)(b * 2048) + qrow) * 768 + h * 64;
#pragma unroll
  for (int dt = 0; dt < 2; ++dt) {
    const f32x16& O = dt ? o1 : o0;
#pragma unroll
    for (int rp = 0; rp < 8; ++rp) {
      int dbase = dt * 32 + (rp & 1) * 2 + (rp >> 1) * 8 + hi * 4;
      float a = O[2 * rp] * inv, bvl = O[2 * rp + 1] * inv;
      unsigned int wpk;
      asm("v_cvt_pk_bf16_f32 %0, %1, %2" : "=v"(wpk) : "v"(a), "v"(bvl));
      *reinterpret_cast<unsigned int*>(Orow + dbase) = wpk;
    }
  }
}

// ---------- launch ----------

extern "C" void kernel_launch(void* const* d_in, const int* in_sizes, int n_in,
                              void* d_out, int out_size, void* d_ws, size_t ws_size,
                              hipStream_t stream) {
  const float* x    = (const float*)d_in[0];
  const float* wqkv = (const float*)d_in[1];
  const float* wout = (const float*)d_in[2];
  const int*   mask = (const int*)d_in[3];
  float* out = (float*)d_out;

  char* ws = (char*)d_ws;
  short* Qb  = (short*)(ws + 0);          // 12.58 MB
  short* Kb  = (short*)(ws + 12582912);   // compacted keys
  short* VT  = (short*)(ws + 25165824);   // [bh][d][s'] compacted
  short* Xbf = (short*)(ws + 37748736);   // x bf16; reused as attn-out bf16
  short* Wq  = (short*)(ws + 50331648);   // permuted: [Q 768 | KV 1536] rows
  short* Wo  = (short*)(ws + 53870592);
  int*   Invp = (int*)(ws + 55050240);    // 4*2048 ints
  int*   Lens = (int*)(ws + 55083008);    // 4 ints

  cvt_scan<<<8452, 256, 0, stream>>>(x, Xbf, wqkv, Wq, wout, Wo,
                                     mask, Invp, Lens);

  gemm_qkv<<<576, 256, 0, stream>>>(Xbf, Wq, Qb, Kb, VT, Invp, Lens);

  attn_kernel<<<48 * 16, 256, 0, stream>>>(Qb, Kb, VT, Lens, Xbf);

  gemm_out<<<64 * 6, 256, 0, stream>>>(Xbf, Wo, out, 8192, 768, 768);
}